// Round 8
// baseline (548.277 us; speedup 1.0000x reference)
//
#include <hip/hip_runtime.h>
#include <math.h>

// MAGNO decoder, MI355X — round 8: 4-wave blocks to break the residency cap.
//   B=2, NL=2048, NQ=16384, CD=2, CIN=H=64, PH=256, COUT=3, K=32, scales {1,2}.
//
// Round-7 post-mortem: VGPR=64 (A[] in AGPRs), LDS 5KB, no spill — yet
// occupancy pinned at ~14 waves/CU and per-SIMD issue ~25% (latency-bound).
// Hypotheses: (a) 1-wave workgroups cap at ~16 wg/CU (CP workgroup slots);
// (b) unified VGPR+AGPR = 128 -> 4 waves/SIMD ceiling. This round tests (a):
//  * block = 256 threads = 4 fully-independent waves, 8 queries/block.
//  * per-wave LDS regions; all __syncthreads -> wave-local
//    s_waitcnt lgkmcnt(0) fences (DS is in-order per wave; no s_barrier).
//  * CAP 224 -> 192 (+13 sigma still): LDS 18.4 KB/block -> 8 blocks/CU
//    = 32 waves/CU if the register file allows.
// Per-lane math is byte-identical to round 7 (verified absmax 1.22e-4):
// lane=edge, wave-uniform s_load weight streaming, pk_fma everywhere,
// branchless A&S-7.1.26 gelu, h1 recompute per group, A[64] resident,
// d2 via __fmul_rn/__fadd_rn (bit-exact radius/top-k decisions), (d2,pos)
// lexicographic top-32 == jax.lax.top_k stable set, halving butterfly
// edge-reduce, fused projection MLP.

#define NLAT 2048
#define NQ_TOT 32768   // B * NQ
#define KNB 32
#define CAP 192        // per-query candidate cap; mean ~78, +13 sigma
#define QPB 8          // queries per block (4 waves x 2)

typedef float f32x2 __attribute__((ext_vector_type(2)));

__device__ __forceinline__ f32x2 pk_fma(f32x2 a, f32x2 b, f32x2 c) {
  return __builtin_elementwise_fma(a, b, c);
}

__device__ __forceinline__ void wave_fence() {
  // Wave-local LDS fence: DS ops are processed in order per wave; this
  // drains outstanding LDS ops so cross-LANE reads see prior writes, and
  // the "memory" clobber stops compiler reordering across the boundary.
  __asm__ volatile("s_waitcnt lgkmcnt(0)" ::: "memory");
}

__device__ __forceinline__ float gelu_fast(float x) {
  // 0.5*x*(1+erf(x/sqrt2)); erf via Abramowitz-Stegun 7.1.26, branchless.
  // |erf err| <= 1.5e-7 abs => gelu err <= ~8e-7 for |x|<=10.
  const float z  = fabsf(x) * 0.70710678118654752440f;
  const float t  = __builtin_amdgcn_rcpf(fmaf(0.3275911f, z, 1.0f));
  const float p  = t * fmaf(t, fmaf(t, fmaf(t, fmaf(t, 1.061405429f,
                                                    -1.453152027f),
                                            1.421413741f),
                                    -0.284496736f),
                            0.254829592f);
  const float ex = exp2f(z * z * -1.4426950408889634f);   // exp(-z^2)
  const float er = copysignf(fmaf(-p, ex, 1.0f), x);       // erf(x/sqrt2)
  return 0.5f * x * (1.0f + er);
}

__global__ __launch_bounds__(256, 2) __attribute__((amdgpu_waves_per_eu(2, 4)))
void magno_fused(const float* __restrict__ lat,   // [NL,2]
                 const float* __restrict__ rn,    // [B,NL,64]
                 const float* __restrict__ qc,    // [B*NQ,2]
                 const float* __restrict__ w_e0, const float* __restrict__ b_e0,
                 const float* __restrict__ w_e1, const float* __restrict__ b_e1,
                 const float* __restrict__ w_e2, const float* __restrict__ b_e2,
                 const float* __restrict__ w_sw0, const float* __restrict__ b_sw0,
                 const float* __restrict__ w_sw1, const float* __restrict__ b_sw1,
                 const float* __restrict__ w_p0, const float* __restrict__ b_p0,
                 const float* __restrict__ w_p1, const float* __restrict__ b_p1,
                 float* __restrict__ out)         // [B*NQ,3]
{
  const float r1sq = (float)(0.055 * 0.055);
  const float r2sq = (float)((0.055 * 2.0) * (0.055 * 2.0));

  // Per-wave private LDS regions (4 waves/block, no cross-wave sharing).
  __shared__ float cd2s[4][2][CAP];               // 6 KB
  __shared__ int   cidxs[4][2][CAP];              // 6 KB
  __shared__ float sd2[4][2][KNB];                // 1 KB
  __shared__ int   sidx[4][2][KNB];               // 1 KB
  __shared__ float u_lds[4][2][64];               // 2 KB
  __shared__ float dec_lds[4][2][64];             // 2 KB

  const int wv   = threadIdx.x >> 6;              // wave in block
  const int lane = threadIdx.x & 63;              // lane in wave
  const int sub  = lane >> 5;                     // wave's query 0/1
  const int e32  = lane & 31;                     // edge slot within query

  // ==== phase 1a: distance pass + compaction (full wave, per query) ========
  int nc0 = 0, nc1 = 0;
#pragma unroll
  for (int s = 0; s < 2; ++s) {
    float* cds = cd2s[wv][s];
    int*   cis = cidxs[wv][s];
    const int gqs = blockIdx.x * QPB + wv * 2 + s;
    const float2 qs = *(const float2*)&qc[2 * gqs];
    int nc = 0;
    for (int t = 0; t < NLAT; t += 64) {
      const int l = t + lane;
      const float2 yv = *(const float2*)&lat[2 * l];
      const float dx = qs.x - yv.x, dy = qs.y - yv.y;
      const float d2 = __fadd_rn(__fmul_rn(dx, dx), __fmul_rn(dy, dy));
      const bool hit = d2 <= r2sq;
      const unsigned long long m = __ballot(hit);
      if (hit) {
        const int pos = nc + __popcll(m & (((unsigned long long)1 << lane) - 1ull));
        if (pos < CAP) { cds[pos] = d2; cis[pos] = l; }
      }
      nc += (int)__popcll(m);
    }
    if (nc > CAP) nc = CAP;    // mean ~78; unreachable
    if (s == 0) nc0 = nc; else nc1 = nc;
  }
  wave_fence();

  // ==== phase 1b: top-32 by (d2,pos), both queries in half-wave parallel ===
  const int ncH = sub ? nc1 : nc0;
  float* cdH = cd2s[wv][sub];
  int*   ciH = cidxs[wv][sub];

  if (ncH <= KNB) {
    if (e32 < ncH) { sd2[wv][sub][e32] = cdH[e32]; sidx[wv][sub][e32] = ciH[e32]; }
  }
  wave_fence();
  if (nc0 > KNB || nc1 > KNB) {                   // wave-uniform condition
    const bool ext = ncH > KNB;
    for (int r = 0; r < KNB; ++r) {
      unsigned long long best = ~0ull;
      if (ext) {
        for (int t = e32; t < ncH; t += 32) {
          const unsigned long long key =
              ((unsigned long long)__float_as_uint(cdH[t]) << 32) | (unsigned)t;
          if (key < best) best = key;
        }
      }
#pragma unroll
      for (int off = 16; off > 0; off >>= 1) {    // butterfly within half-wave
        const unsigned long long o = __shfl_xor(best, off);
        if (o < best) best = o;
      }
      if (ext && e32 == 0) {
        const int pos = (int)(best & 0xffffffffu);
        sd2[wv][sub][r]  = __uint_as_float((unsigned)(best >> 32));
        sidx[wv][sub][r] = ciH[pos];
        cdH[pos] = __uint_as_float(0x7f800000u);  // +inf: claimed
      }
      wave_fence();
    }
  }
  const int n_sel = ncH < KNB ? ncH : KNB;

  // ==== phase 2 setup: lane = edge =========================================
  const int gq = blockIdx.x * QPB + wv * 2 + sub;
  const int bb = gq >> 14;                        // batch = gq / NQ
  const float2 qv = *(const float2*)&qc[2 * gq];

  const bool  active = e32 < n_sel;
  const float d2e = active ? sd2[wv][sub][e32] : 1e30f;
  const int   ie  = active ? sidx[wv][sub][e32] : 0;
  const float2 yv = *(const float2*)&lat[2 * ie];

  // u table: u_i = qx*w_e0[128+i] + qy*w_e0[192+i] + b_e0[i] (per query).
  // lane (sub,e32) computes channels 2*e32, 2*e32+1 of its query.
  {
    const f32x2 w2p = *(const f32x2*)&w_e0[128 + 2 * e32];
    const f32x2 w3p = *(const f32x2*)&w_e0[192 + 2 * e32];
    const f32x2 bp  = *(const f32x2*)&b_e0[2 * e32];
    const f32x2 qx2 = {qv.x, qv.x}, qy2 = {qv.y, qv.y};
    const f32x2 u2 = pk_fma(qx2, w2p, pk_fma(qy2, w3p, bp));
    *(f32x2*)&u_lds[wv][sub][2 * e32] = u2;
  }
  wave_fence();

  // ==== phase 2: edge MLP, h1 recomputed per group, A resident =============
  float A_[64];                                   // layer-2 accumulators
  f32x2* A = (f32x2*)A_;
#pragma unroll
  for (int j = 0; j < 32; ++j) A[j] = *(const f32x2*)&b_e2[2 * j];

  const f32x2 yx2 = {yv.x, yv.x}, yy2 = {yv.y, yv.y};

#pragma unroll 1
  for (int g = 0; g < 2; ++g) {                   // 2 groups of 32 h2 channels
    f32x2 L[16];
#pragma unroll
    for (int k = 0; k < 16; ++k) L[k] = *(const f32x2*)&b_e1[g * 32 + 2 * k];

    // layer 1 for this group; h1 recomputed pairwise (u from LDS broadcast)
#pragma unroll 4
    for (int i = 0; i < 64; i += 2) {
      const f32x2 w0p = *(const f32x2*)&w_e0[i];           // s_load (uniform)
      const f32x2 w1p = *(const f32x2*)&w_e0[64 + i];
      const f32x2 u2  = *(const f32x2*)&u_lds[wv][sub][i]; // ds broadcast
      const f32x2 t2  = pk_fma(yx2, w0p, pk_fma(yy2, w1p, u2));
      const float ha = gelu_fast(t2.x);
      const float hb = gelu_fast(t2.y);
      const f32x2 ha2 = {ha, ha}, hb2 = {hb, hb};
      const f32x2* wrA = (const f32x2*)&w_e1[i * 64 + g * 32];
      const f32x2* wrB = (const f32x2*)&w_e1[(i + 1) * 64 + g * 32];
#pragma unroll
      for (int k = 0; k < 16; ++k) L[k] = pk_fma(ha2, wrA[k], L[k]);
#pragma unroll
      for (int k = 0; k < 16; ++k) L[k] = pk_fma(hb2, wrB[k], L[k]);
    }

    // layer 2: consume this group's 32 h2 channels immediately
#pragma unroll
    for (int kk = 0; kk < 32; ++kk) {
      const float h2v = gelu_fast((kk & 1) ? L[kk >> 1].y : L[kk >> 1].x);
      const f32x2 h2 = {h2v, h2v};
      const f32x2* w2r = (const f32x2*)&w_e2[(g * 32 + kk) * 64];
#pragma unroll
      for (int j = 0; j < 32; ++j) A[j] = pk_fma(h2, w2r[j], A[j]);
    }
  }

  // ==== phase 3: scale-mix softmax + per-edge factor ========================
  float z0 = b_sw1[0], z1 = b_sw1[1];
#pragma unroll
  for (int k = 0; k < 16; ++k) {
    float t = fmaf(qv.x, w_sw0[k], fmaf(qv.y, w_sw0[16 + k], b_sw0[k]));
    t = fmaxf(t, 0.f);
    z0 = fmaf(t, w_sw1[2 * k + 0], z0);
    z1 = fmaf(t, w_sw1[2 * k + 1], z1);
  }
  const float mz = fmaxf(z0, z1);
  const float ex0 = expf(z0 - mz), ex1 = expf(z1 - mz);
  const float inv = 1.f / (ex0 + ex1);
  const float sw0 = ex0 * inv, sw1 = ex1 * inv;   // sw0<->scale1, sw1<->scale2

  const bool v1 = active && (d2e <= r1sq);
  const unsigned long long mB = __ballot(v1);
  const int cnt1 = (int)__popcll((mB >> (lane & 32)) & 0xffffffffull);
  float fac = 0.f;
  if (active) {
    fac = sw1 / (float)n_sel;
    if (v1) fac += sw0 / (float)cnt1;
  }
  const f32x2 fac2 = {fac, fac};

  // ==== phase 4: finalize + halving butterfly edge-reduce ===================
  const float* rnp = rn + ((size_t)bb * NLAT + ie) * 64;

#pragma unroll
  for (int c = 0; c < 2; ++c) {                   // 2 chunks of 32 channels
    float v[32];
#pragma unroll
    for (int j = 0; j < 8; ++j) {
      const float4 r4 = *(const float4*)&rnp[c * 32 + 4 * j];
      f32x2 m0 = A[c * 16 + 2 * j]     * (f32x2){r4.x, r4.y} * fac2;
      f32x2 m1 = A[c * 16 + 2 * j + 1] * (f32x2){r4.z, r4.w} * fac2;
      v[4 * j + 0] = m0.x; v[4 * j + 1] = m0.y;
      v[4 * j + 2] = m1.x; v[4 * j + 3] = m1.y;
    }

    float w16[16];
    { const bool up = (e32 & 1);
#pragma unroll
      for (int k = 0; k < 16; ++k) {
        const float keep = up ? v[16 + k] : v[k];
        const float send = up ? v[k] : v[16 + k];
        w16[k] = keep + __shfl_xor(send, 1);
      } }
    float w8[8];
    { const bool up = (e32 & 2);
#pragma unroll
      for (int k = 0; k < 8; ++k) {
        const float keep = up ? w16[8 + k] : w16[k];
        const float send = up ? w16[k] : w16[8 + k];
        w8[k] = keep + __shfl_xor(send, 2);
      } }
    float w4[4];
    { const bool up = (e32 & 4);
#pragma unroll
      for (int k = 0; k < 4; ++k) {
        const float keep = up ? w8[4 + k] : w8[k];
        const float send = up ? w8[k] : w8[4 + k];
        w4[k] = keep + __shfl_xor(send, 4);
      } }
    float w2[2];
    { const bool up = (e32 & 8);
#pragma unroll
      for (int k = 0; k < 2; ++k) {
        const float keep = up ? w4[2 + k] : w4[k];
        const float send = up ? w4[k] : w4[2 + k];
        w2[k] = keep + __shfl_xor(send, 8);
      } }
    float w1;
    { const bool up = (e32 & 16);
      const float keep = up ? w2[1] : w2[0];
      const float send = up ? w2[0] : w2[1];
      w1 = keep + __shfl_xor(send, 16); }

    // lane owns channel bitrev5(e32) of this chunk (bijection on 0..31)
    const int cl = ((e32 & 1) << 4) | ((e32 & 2) << 2) | (e32 & 4) |
                   ((e32 & 8) >> 2) | ((e32 & 16) >> 4);
    dec_lds[wv][sub][c * 32 + cl] = w1;
  }
  wave_fence();                                   // dec_lds cross-lane reads

  // ==== phase 5: projection MLP: lane owns PH channels e32*8 .. e32*8+7 ====
  f32x2 ph2[4];
  {
    const float4 ba = *(const float4*)&b_p0[e32 * 8];
    const float4 bc = *(const float4*)&b_p0[e32 * 8 + 4];
    ph2[0] = (f32x2){ba.x, ba.y}; ph2[1] = (f32x2){ba.z, ba.w};
    ph2[2] = (f32x2){bc.x, bc.y}; ph2[3] = (f32x2){bc.z, bc.w};
  }
#pragma unroll 4
  for (int i = 0; i < 64; ++i) {
    const float di = dec_lds[wv][sub][i];         // LDS broadcast per half
    const f32x2 di2 = {di, di};
    const float4 wa = *(const float4*)&w_p0[i * 256 + e32 * 8];
    const float4 wb = *(const float4*)&w_p0[i * 256 + e32 * 8 + 4];
    ph2[0] = pk_fma(di2, (f32x2){wa.x, wa.y}, ph2[0]);
    ph2[1] = pk_fma(di2, (f32x2){wa.z, wa.w}, ph2[1]);
    ph2[2] = pk_fma(di2, (f32x2){wb.x, wb.y}, ph2[2]);
    ph2[3] = pk_fma(di2, (f32x2){wb.z, wb.w}, ph2[3]);
  }

  float o0 = 0.f, o1 = 0.f, o2 = 0.f;
#pragma unroll
  for (int k = 0; k < 8; ++k) {
    const float pv = (k & 1) ? ph2[k >> 1].y : ph2[k >> 1].x;
    const float gk = gelu_fast(pv);
    const int row = e32 * 8 + k;
    o0 = fmaf(gk, w_p1[row * 3 + 0], o0);
    o1 = fmaf(gk, w_p1[row * 3 + 1], o1);
    o2 = fmaf(gk, w_p1[row * 3 + 2], o2);
  }
#pragma unroll
  for (int off = 1; off < 32; off <<= 1) {
    o0 += __shfl_xor(o0, off);
    o1 += __shfl_xor(o1, off);
    o2 += __shfl_xor(o2, off);
  }
  if (e32 == 0) {
    out[(size_t)gq * 3 + 0] = o0 + b_p1[0];
    out[(size_t)gq * 3 + 1] = o1 + b_p1[1];
    out[(size_t)gq * 3 + 2] = o2 + b_p1[2];
  }
}

extern "C" void kernel_launch(void* const* d_in, const int* in_sizes, int n_in,
                              void* d_out, int out_size, void* d_ws, size_t ws_size,
                              hipStream_t stream) {
  const float* lat   = (const float*)d_in[0];
  const float* rn    = (const float*)d_in[1];
  const float* qc    = (const float*)d_in[2];
  const float* w_e0  = (const float*)d_in[3];
  const float* b_e0  = (const float*)d_in[4];
  const float* w_e1  = (const float*)d_in[5];
  const float* b_e1  = (const float*)d_in[6];
  const float* w_e2  = (const float*)d_in[7];
  const float* b_e2  = (const float*)d_in[8];
  const float* w_sw0 = (const float*)d_in[9];
  const float* b_sw0 = (const float*)d_in[10];
  const float* w_sw1 = (const float*)d_in[11];
  const float* b_sw1 = (const float*)d_in[12];
  const float* w_p0  = (const float*)d_in[13];
  const float* b_p0  = (const float*)d_in[14];
  const float* w_p1  = (const float*)d_in[15];
  const float* b_p1  = (const float*)d_in[16];

  float* out = (float*)d_out;

  hipLaunchKernelGGL(magno_fused, dim3(NQ_TOT / QPB), dim3(256), 0, stream,
                     lat, rn, qc, w_e0, b_e0, w_e1, b_e1, w_e2, b_e2,
                     w_sw0, b_sw0, w_sw1, b_sw1, w_p0, b_p0, w_p1, b_p1, out);
}

// Round 10
// 431.803 us; speedup vs baseline: 1.2697x; 1.2697x over previous
//
#include <hip/hip_runtime.h>
#include <math.h>

// MAGNO decoder, MI355X — round 9 (resubmit; r9 bench never acquired a GPU).
// MFMA edge-MLP (bf16 2-split, 3 products).
//   B=2, NL=2048, NQ=16384, CD=2, CIN=H=64, PH=256, COUT=3, K=32, scales {1,2}.
//
// r8 post-mortem: fp32-VALU design measured ~97% issue-efficient when busy;
// floor ~360-400us. The 219us of edge-MLP MACs moves to the matrix pipe:
//  * per wave (2 queries = 64 edge-rows): layer = 64x64x64 GEMM =
//    16 tiles of mfma_f32_16x16x32_bf16 x 2 K-steps x 3 split-products
//    = 96 MFMA/layer (hi*hi + hi*lo + lo*hi; dropped lo*lo ~2^-32).
//  * A/B fragment map: row/col = lane&15, k = 8*(lane>>4)+e (+32*kt).
//    C/D map (HW-verified): col = lane&15, row = (lane>>4)*4 + reg.
//    A and B use the SAME k-map, so any within-lane k-permutation cancels.
//  * Weights pre-split to bf16 hi/lo and pre-laid-out in B-fragment order in
//    d_ws by prep_wfrag -> per-frag load is one coalesced dwordx4.
//  * X-frags (layer-1 A) built in registers straight from layer-0 math
//    (h1 never materializes). h2 goes through a [64][40]-bf16 hi+lo LDS
//    half-buffer (two 32-ch halves); layer-2 acc persists in 16 f32x4 (AGPR).
//  * Selection/softmax/fac/proj machinery: r8-verified code, unchanged.
// LDS/wave ~12.8KB (candidates overlay the h2 planes); 4-wave blocks.

#define NLAT 2048
#define NQ_TOT 32768   // B * NQ
#define KNB 32
#define CAP 192        // per-query candidate cap; mean ~78, +13 sigma
#define QPB 8          // queries per block (4 waves x 2)

typedef float f32x2 __attribute__((ext_vector_type(2)));
typedef short s16x8 __attribute__((ext_vector_type(8)));
typedef float f32x4v __attribute__((ext_vector_type(4)));

__device__ __forceinline__ f32x2 pk_fma(f32x2 a, f32x2 b, f32x2 c) {
  return __builtin_elementwise_fma(a, b, c);
}

__device__ __forceinline__ void wave_fence() {
  __asm__ volatile("s_waitcnt lgkmcnt(0)" ::: "memory");
}

__device__ __forceinline__ unsigned short f2bf(float f) {   // RNE fp32->bf16
  unsigned int u = __float_as_uint(f);
  return (unsigned short)((u + 0x7fffu + ((u >> 16) & 1u)) >> 16);
}
__device__ __forceinline__ float bf2f(unsigned short h) {
  return __uint_as_float(((unsigned int)h) << 16);
}

__device__ __forceinline__ f32x4v MFMA(int4 a, int4 b, f32x4v c) {
  return __builtin_amdgcn_mfma_f32_16x16x32_bf16(
      __builtin_bit_cast(s16x8, a), __builtin_bit_cast(s16x8, b), c, 0, 0, 0);
}

__device__ __forceinline__ float gelu_fast(float x) {
  // 0.5*x*(1+erf(x/sqrt2)); A&S 7.1.26 branchless; |err| <= ~8e-7.
  const float z  = fabsf(x) * 0.70710678118654752440f;
  const float t  = __builtin_amdgcn_rcpf(fmaf(0.3275911f, z, 1.0f));
  const float p  = t * fmaf(t, fmaf(t, fmaf(t, fmaf(t, 1.061405429f,
                                                    -1.453152027f),
                                            1.421413741f),
                                    -0.284496736f),
                            0.254829592f);
  const float ex = exp2f(z * z * -1.4426950408889634f);
  const float er = copysignf(fmaf(-p, ex, 1.0f), x);
  return 0.5f * x * (1.0f + er);
}

// ---- prep: split w_e1/w_e2 to bf16 hi/lo in B-fragment order --------------
// ws u32 index: ((((layer*4+ct)*2+kt)*2+hl)*64+lane)*4+reg ; 8192 u32 = 32KB.
__global__ __launch_bounds__(256)
void prep_wfrag(const float* __restrict__ w_e1, const float* __restrict__ w_e2,
                unsigned int* __restrict__ wsout) {
  const int t = blockIdx.x * 256 + threadIdx.x;
  if (t >= 8192) return;
  const int reg = t & 3, lane = (t >> 2) & 63, hl = (t >> 8) & 1;
  const int kt = (t >> 9) & 1, ct = (t >> 10) & 3, layer = (t >> 12) & 1;
  const int g = lane >> 4, c = lane & 15;
  const int col = c + 16 * ct;
  const int k0 = 8 * g + 2 * reg + 32 * kt;
  const float* W = layer ? w_e2 : w_e1;               // [k][col] row-major 64
  const float f0 = W[k0 * 64 + col], f1 = W[(k0 + 1) * 64 + col];
  const unsigned short h0 = f2bf(f0), h1 = f2bf(f1);
  unsigned int v;
  if (hl == 0) {
    v = (unsigned int)h0 | ((unsigned int)h1 << 16);
  } else {
    const unsigned short l0 = f2bf(f0 - bf2f(h0));
    const unsigned short l1 = f2bf(f1 - bf2f(h1));
    v = (unsigned int)l0 | ((unsigned int)l1 << 16);
  }
  wsout[t] = v;
}

// ---- main -----------------------------------------------------------------
__global__ __launch_bounds__(256, 2)
void magno_fused(const float* __restrict__ lat,   // [NL,2]
                 const float* __restrict__ rn,    // [B,NL,64]
                 const float* __restrict__ qc,    // [B*NQ,2]
                 const float* __restrict__ w_e0, const float* __restrict__ b_e0,
                 const float* __restrict__ b_e1, const float* __restrict__ b_e2,
                 const float* __restrict__ w_sw0, const float* __restrict__ b_sw0,
                 const float* __restrict__ w_sw1, const float* __restrict__ b_sw1,
                 const float* __restrict__ w_p0, const float* __restrict__ b_p0,
                 const float* __restrict__ w_p1, const float* __restrict__ b_p1,
                 const int4* __restrict__ wf,     // B-fragments (prep output)
                 float* __restrict__ out)         // [B*NQ,3]
{
  const float r1sq = (float)(0.055 * 0.055);
  const float r2sq = (float)((0.055 * 2.0) * (0.055 * 2.0));

  // wbig[wv]: u32[2560] = 10240B. Phase 1: candidate overlay
  //   (cd2 q0/q1 = float[384] at u32 0.., cidx q0/q1 = int[384] at u32 1280..).
  // Phase 2: h2 planes: hi = ushort[2560] at u32 0, lo = ushort[2560] at 1280.
  // Plane layout [64 edge][40 ch-local] bf16, stride 80B (16B-aligned rows).
  __shared__ unsigned int wbig[4][2560];
  __shared__ float sd2[4][2][KNB];
  __shared__ int   sidx[4][2][KNB];
  __shared__ float eyx[4][64], eyy[4][64], efac[4][64];
  __shared__ int   ernb[4][64];
  __shared__ float u_lds[4][2][64];
  __shared__ float dec_lds[4][2][64];

  const int wv   = threadIdx.x >> 6;
  const int lane = threadIdx.x & 63;
  const int sub  = lane >> 5;
  const int e32  = lane & 31;
  const int g    = lane >> 4;                     // MFMA lane group
  const int c    = lane & 15;                     // MFMA row/col within tile

  float* cdW = (float*)&wbig[wv][0];
  int*   ciW = (int*)&wbig[wv][1280];
  unsigned short* h2h = (unsigned short*)&wbig[wv][0];
  unsigned short* h2l = (unsigned short*)&wbig[wv][1280];

  // ==== phase 1a: distance pass + compaction (r8-verified) =================
  int nc0 = 0, nc1 = 0;
#pragma unroll
  for (int s = 0; s < 2; ++s) {
    float* cds = cdW + s * CAP;
    int*   cis = ciW + s * CAP;
    const int gqs = blockIdx.x * QPB + wv * 2 + s;
    const float2 qs = *(const float2*)&qc[2 * gqs];
    int nc = 0;
    for (int t = 0; t < NLAT; t += 64) {
      const int l = t + lane;
      const float2 yv = *(const float2*)&lat[2 * l];
      const float dx = qs.x - yv.x, dy = qs.y - yv.y;
      const float d2 = __fadd_rn(__fmul_rn(dx, dx), __fmul_rn(dy, dy));
      const bool hit = d2 <= r2sq;
      const unsigned long long m = __ballot(hit);
      if (hit) {
        const int pos = nc + __popcll(m & (((unsigned long long)1 << lane) - 1ull));
        if (pos < CAP) { cds[pos] = d2; cis[pos] = l; }
      }
      nc += (int)__popcll(m);
    }
    if (nc > CAP) nc = CAP;
    if (s == 0) nc0 = nc; else nc1 = nc;
  }
  wave_fence();

  // ==== phase 1b: top-32 by (d2,pos), half-wave parallel (r8-verified) =====
  const int ncH = sub ? nc1 : nc0;
  float* cdH = cdW + sub * CAP;
  int*   ciH = ciW + sub * CAP;

  if (ncH <= KNB) {
    if (e32 < ncH) { sd2[wv][sub][e32] = cdH[e32]; sidx[wv][sub][e32] = ciH[e32]; }
  }
  wave_fence();
  if (nc0 > KNB || nc1 > KNB) {
    const bool ext = ncH > KNB;
    for (int r = 0; r < KNB; ++r) {
      unsigned long long best = ~0ull;
      if (ext) {
        for (int t = e32; t < ncH; t += 32) {
          const unsigned long long key =
              ((unsigned long long)__float_as_uint(cdH[t]) << 32) | (unsigned)t;
          if (key < best) best = key;
        }
      }
#pragma unroll
      for (int off = 16; off > 0; off >>= 1) {
        const unsigned long long o = __shfl_xor(best, off);
        if (o < best) best = o;
      }
      if (ext && e32 == 0) {
        const int pos = (int)(best & 0xffffffffu);
        sd2[wv][sub][r]  = __uint_as_float((unsigned)(best >> 32));
        sidx[wv][sub][r] = ciH[pos];
        cdH[pos] = __uint_as_float(0x7f800000u);
      }
      wave_fence();
    }
  }
  const int n_sel = ncH < KNB ? ncH : KNB;

  // ==== phase 1c: per-edge metadata (lane = edge), fac, u-table ============
  const int gq = blockIdx.x * QPB + wv * 2 + sub;
  const int bb = gq >> 14;
  const float2 qv = *(const float2*)&qc[2 * gq];

  const bool  active = e32 < n_sel;
  const float d2e = active ? sd2[wv][sub][e32] : 1e30f;
  const int   ie  = active ? sidx[wv][sub][e32] : 0;
  const float2 yv = *(const float2*)&lat[2 * ie];

  float z0 = b_sw1[0], z1 = b_sw1[1];
#pragma unroll
  for (int k = 0; k < 16; ++k) {
    float t = fmaf(qv.x, w_sw0[k], fmaf(qv.y, w_sw0[16 + k], b_sw0[k]));
    t = fmaxf(t, 0.f);
    z0 = fmaf(t, w_sw1[2 * k + 0], z0);
    z1 = fmaf(t, w_sw1[2 * k + 1], z1);
  }
  const float mz = fmaxf(z0, z1);
  const float ex0 = expf(z0 - mz), ex1 = expf(z1 - mz);
  const float inv = 1.f / (ex0 + ex1);
  const float sw0 = ex0 * inv, sw1 = ex1 * inv;

  const bool v1 = active && (d2e <= r1sq);
  const unsigned long long mB = __ballot(v1);
  const int cnt1 = (int)__popcll((mB >> (lane & 32)) & 0xffffffffull);
  float fac = 0.f;
  if (active) {
    fac = sw1 / (float)n_sel;
    if (v1) fac += sw0 / (float)cnt1;
  }

  eyx[wv][lane]  = yv.x;
  eyy[wv][lane]  = yv.y;
  efac[wv][lane] = fac;
  ernb[wv][lane] = (bb * NLAT + ie) * 64;
  {
    const f32x2 w2p = *(const f32x2*)&w_e0[128 + 2 * e32];
    const f32x2 w3p = *(const f32x2*)&w_e0[192 + 2 * e32];
    const f32x2 bp  = *(const f32x2*)&b_e0[2 * e32];
    const f32x2 qx2 = {qv.x, qv.x}, qy2 = {qv.y, qv.y};
    *(f32x2*)&u_lds[wv][sub][2 * e32] = pk_fma(qx2, w2p, pk_fma(qy2, w3p, bp));
  }
  wave_fence();

  // ==== phase 2a: X-fragments (layer-1 A) in registers =====================
  // lane holds rows (edge = c+16rt), k-slice 8g+e+32kt, as bf16 hi/lo.
  int4 Xhi[4][2], Xlo[4][2];
#pragma unroll
  for (int rt = 0; rt < 4; ++rt) {
    const int edge = c + 16 * rt;
    const float yx = eyx[wv][edge], yy = eyy[wv][edge];
    const float* uq = u_lds[wv][rt >> 1];
#pragma unroll
    for (int kt = 0; kt < 2; ++kt) {
      const int ch = 8 * g + 32 * kt;
      const float4 wa0 = *(const float4*)&w_e0[ch];
      const float4 wa1 = *(const float4*)&w_e0[ch + 4];
      const float4 wb0 = *(const float4*)&w_e0[64 + ch];
      const float4 wb1 = *(const float4*)&w_e0[64 + ch + 4];
      const float4 uu0 = *(const float4*)&uq[ch];
      const float4 uu1 = *(const float4*)&uq[ch + 4];
      float v[8];
      v[0] = fmaf(yx, wa0.x, fmaf(yy, wb0.x, uu0.x));
      v[1] = fmaf(yx, wa0.y, fmaf(yy, wb0.y, uu0.y));
      v[2] = fmaf(yx, wa0.z, fmaf(yy, wb0.z, uu0.z));
      v[3] = fmaf(yx, wa0.w, fmaf(yy, wb0.w, uu0.w));
      v[4] = fmaf(yx, wa1.x, fmaf(yy, wb1.x, uu1.x));
      v[5] = fmaf(yx, wa1.y, fmaf(yy, wb1.y, uu1.y));
      v[6] = fmaf(yx, wa1.z, fmaf(yy, wb1.z, uu1.z));
      v[7] = fmaf(yx, wa1.w, fmaf(yy, wb1.w, uu1.w));
      unsigned short hi[8], lo[8];
#pragma unroll
      for (int e = 0; e < 8; ++e) {
        const float xg = gelu_fast(v[e]);
        hi[e] = f2bf(xg);
        lo[e] = f2bf(xg - bf2f(hi[e]));
      }
      Xhi[rt][kt] = make_int4((int)((unsigned)hi[0] | ((unsigned)hi[1] << 16)),
                              (int)((unsigned)hi[2] | ((unsigned)hi[3] << 16)),
                              (int)((unsigned)hi[4] | ((unsigned)hi[5] << 16)),
                              (int)((unsigned)hi[6] | ((unsigned)hi[7] << 16)));
      Xlo[rt][kt] = make_int4((int)((unsigned)lo[0] | ((unsigned)lo[1] << 16)),
                              (int)((unsigned)lo[2] | ((unsigned)lo[3] << 16)),
                              (int)((unsigned)lo[4] | ((unsigned)lo[5] << 16)),
                              (int)((unsigned)lo[6] | ((unsigned)lo[7] << 16)));
    }
  }

  // ==== phase 2b: layer1 -> h2 halves -> layer2 (acc persists) =============
  f32x4v acc2[4][4];
#pragma unroll
  for (int ct2 = 0; ct2 < 4; ++ct2) {
    const float b2 = b_e2[16 * ct2 + c];
    const f32x4v bv = {b2, b2, b2, b2};
#pragma unroll
    for (int rt = 0; rt < 4; ++rt) acc2[rt][ct2] = bv;
  }

#pragma unroll
  for (int half = 0; half < 2; ++half) {
    // layer 1, output-channel half: ct1 = 2*half + cc, local ch = 16*cc + c
#pragma unroll
    for (int cc = 0; cc < 2; ++cc) {
      const int ct1 = 2 * half + cc;
      const float b1 = b_e1[16 * ct1 + c];
      const int4 B1h0 = wf[(((ct1 * 2 + 0) * 2 + 0)) * 64 + lane];
      const int4 B1l0 = wf[(((ct1 * 2 + 0) * 2 + 1)) * 64 + lane];
      const int4 B1h1 = wf[(((ct1 * 2 + 1) * 2 + 0)) * 64 + lane];
      const int4 B1l1 = wf[(((ct1 * 2 + 1) * 2 + 1)) * 64 + lane];
#pragma unroll
      for (int rt = 0; rt < 4; ++rt) {
        f32x4v a = {b1, b1, b1, b1};
        a = MFMA(Xhi[rt][0], B1h0, a);
        a = MFMA(Xhi[rt][0], B1l0, a);
        a = MFMA(Xlo[rt][0], B1h0, a);
        a = MFMA(Xhi[rt][1], B1h1, a);
        a = MFMA(Xhi[rt][1], B1l1, a);
        a = MFMA(Xlo[rt][1], B1h1, a);
#pragma unroll
        for (int r = 0; r < 4; ++r) {
          const float hv = gelu_fast(a[r]);
          const unsigned short hh = f2bf(hv);
          const unsigned short hl_ = f2bf(hv - bf2f(hh));
          const int edge = 16 * rt + 4 * g + r;       // D row (verified map)
          const int chl  = 16 * cc + c;               // D col (verified map)
          h2h[edge * 40 + chl] = hh;
          h2l[edge * 40 + chl] = hl_;
        }
      }
    }
    wave_fence();                                     // h2 half ready

    // layer 2, K-half = this h2 half
#pragma unroll
    for (int ct2 = 0; ct2 < 4; ++ct2) {
      const int4 B2h = wf[((((4 + ct2) * 2 + half) * 2 + 0)) * 64 + lane];
      const int4 B2l = wf[((((4 + ct2) * 2 + half) * 2 + 1)) * 64 + lane];
#pragma unroll
      for (int rt = 0; rt < 4; ++rt) {
        const int row = c + 16 * rt;
        const int4 A2h = *(const int4*)&h2h[row * 40 + 8 * g];
        const int4 A2l = *(const int4*)&h2l[row * 40 + 8 * g];
        acc2[rt][ct2] = MFMA(A2h, B2h, acc2[rt][ct2]);
        acc2[rt][ct2] = MFMA(A2h, B2l, acc2[rt][ct2]);
        acc2[rt][ct2] = MFMA(A2l, B2h, acc2[rt][ct2]);
      }
    }
    wave_fence();                                     // reads done before overwrite
  }

  // ==== phase 3: finalize h3*rn*fac, reduce over edges -> dec ==============
  float dec_reg[2][4] = {{0.f, 0.f, 0.f, 0.f}, {0.f, 0.f, 0.f, 0.f}};
#pragma unroll
  for (int rt = 0; rt < 4; ++rt) {
    int   eb[4];
    float ef[4];
#pragma unroll
    for (int r = 0; r < 4; ++r) {
      const int edge = 16 * rt + 4 * g + r;
      eb[r] = ernb[wv][edge];
      ef[r] = efac[wv][edge];
    }
#pragma unroll
    for (int ct2 = 0; ct2 < 4; ++ct2) {
      const f32x4v a = acc2[rt][ct2];
      float s = 0.f;
#pragma unroll
      for (int r = 0; r < 4; ++r) {
        const float rnv = rn[eb[r] + 16 * ct2 + c];
        s = fmaf(a[r] * ef[r], rnv, s);
      }
      s += __shfl_xor(s, 16);
      s += __shfl_xor(s, 32);
      dec_reg[rt >> 1][ct2] += s;
    }
  }
  if (g == 0) {
#pragma unroll
    for (int q = 0; q < 2; ++q)
#pragma unroll
      for (int ct2 = 0; ct2 < 4; ++ct2)
        dec_lds[wv][q][16 * ct2 + c] = dec_reg[q][ct2];
  }
  wave_fence();

  // ==== phase 4: projection MLP (r8-verified) ==============================
  f32x2 ph2[4];
  {
    const float4 ba = *(const float4*)&b_p0[e32 * 8];
    const float4 bc = *(const float4*)&b_p0[e32 * 8 + 4];
    ph2[0] = (f32x2){ba.x, ba.y}; ph2[1] = (f32x2){ba.z, ba.w};
    ph2[2] = (f32x2){bc.x, bc.y}; ph2[3] = (f32x2){bc.z, bc.w};
  }
#pragma unroll 4
  for (int i = 0; i < 64; ++i) {
    const float di = dec_lds[wv][sub][i];
    const f32x2 di2 = {di, di};
    const float4 wa = *(const float4*)&w_p0[i * 256 + e32 * 8];
    const float4 wb = *(const float4*)&w_p0[i * 256 + e32 * 8 + 4];
    ph2[0] = pk_fma(di2, (f32x2){wa.x, wa.y}, ph2[0]);
    ph2[1] = pk_fma(di2, (f32x2){wa.z, wa.w}, ph2[1]);
    ph2[2] = pk_fma(di2, (f32x2){wb.x, wb.y}, ph2[2]);
    ph2[3] = pk_fma(di2, (f32x2){wb.z, wb.w}, ph2[3]);
  }

  float o0 = 0.f, o1 = 0.f, o2 = 0.f;
#pragma unroll
  for (int k = 0; k < 8; ++k) {
    const float pv = (k & 1) ? ph2[k >> 1].y : ph2[k >> 1].x;
    const float gk = gelu_fast(pv);
    const int row = e32 * 8 + k;
    o0 = fmaf(gk, w_p1[row * 3 + 0], o0);
    o1 = fmaf(gk, w_p1[row * 3 + 1], o1);
    o2 = fmaf(gk, w_p1[row * 3 + 2], o2);
  }
#pragma unroll
  for (int off = 1; off < 32; off <<= 1) {
    o0 += __shfl_xor(o0, off);
    o1 += __shfl_xor(o1, off);
    o2 += __shfl_xor(o2, off);
  }
  if (e32 == 0) {
    out[(size_t)gq * 3 + 0] = o0 + b_p1[0];
    out[(size_t)gq * 3 + 1] = o1 + b_p1[1];
    out[(size_t)gq * 3 + 2] = o2 + b_p1[2];
  }
}

extern "C" void kernel_launch(void* const* d_in, const int* in_sizes, int n_in,
                              void* d_out, int out_size, void* d_ws, size_t ws_size,
                              hipStream_t stream) {
  const float* lat   = (const float*)d_in[0];
  const float* rn    = (const float*)d_in[1];
  const float* qc    = (const float*)d_in[2];
  const float* w_e0  = (const float*)d_in[3];
  const float* b_e0  = (const float*)d_in[4];
  const float* w_e1  = (const float*)d_in[5];
  const float* b_e1  = (const float*)d_in[6];
  const float* w_e2  = (const float*)d_in[7];
  const float* b_e2  = (const float*)d_in[8];
  const float* w_sw0 = (const float*)d_in[9];
  const float* b_sw0 = (const float*)d_in[10];
  const float* w_sw1 = (const float*)d_in[11];
  const float* b_sw1 = (const float*)d_in[12];
  const float* w_p0  = (const float*)d_in[13];
  const float* b_p0  = (const float*)d_in[14];
  const float* w_p1  = (const float*)d_in[15];
  const float* b_p1  = (const float*)d_in[16];

  unsigned int* wsu = (unsigned int*)d_ws;   // 32KB of weight fragments
  float* out = (float*)d_out;

  hipLaunchKernelGGL(prep_wfrag, dim3(32), dim3(256), 0, stream, w_e1, w_e2, wsu);
  hipLaunchKernelGGL(magno_fused, dim3(NQ_TOT / QPB), dim3(256), 0, stream,
                     lat, rn, qc, w_e0, b_e0, b_e1, b_e2,
                     w_sw0, b_sw0, w_sw1, b_sw1, w_p0, b_p0, w_p1, b_p1,
                     (const int4*)wsu, out);
}